// Round 14
// baseline (60760.364 us; speedup 1.0000x reference)
//
#include <hip/hip_runtime.h>
#include <math.h>

#define IN_SIZE 96
#define HID 128
#define H3 384
#define LIN_IN 32

// ---------------------------------------------------------------------------
// Kernel A (parallel): igates[t][j] = dot(input_GRU[t,:], w_ih[j,:]) + b_ih[j]
// ---------------------------------------------------------------------------
__global__ __launch_bounds__(384, 2)
void igates_kernel(const float* __restrict__ x, const float* __restrict__ w_ih,
                   const float* __restrict__ b_ih, float* __restrict__ ig, int T)
{
    const int TT = 16;
    int t0 = blockIdx.x * TT;
    int j = threadIdx.x; // 0..383
    __shared__ __align__(16) float xs[TT * IN_SIZE]; // 6 KB
    for (int idx = j; idx < TT * IN_SIZE; idx += H3)
        xs[idx] = x[(size_t)t0 * IN_SIZE + idx];
    __syncthreads();

    float acc[TT];
    float b = b_ih[j];
#pragma unroll
    for (int tt = 0; tt < TT; tt++) acc[tt] = b;

    const float4* w4 = (const float4*)(w_ih + (size_t)j * IN_SIZE);
#pragma unroll
    for (int k = 0; k < IN_SIZE / 4; k++) {
        float4 wv = w4[k];
#pragma unroll
        for (int tt = 0; tt < TT; tt++) {
            const float4* xv4 = (const float4*)(xs + tt * IN_SIZE);
            float4 xv = xv4[k];
            acc[tt] = fmaf(wv.x, xv.x, acc[tt]);
            acc[tt] = fmaf(wv.y, xv.y, acc[tt]);
            acc[tt] = fmaf(wv.z, xv.z, acc[tt]);
            acc[tt] = fmaf(wv.w, xv.w, acc[tt]);
        }
    }
#pragma unroll
    for (int tt = 0; tt < TT; tt++)
        ig[(size_t)(t0 + tt) * H3 + j] = acc[tt];
}

// ---------------------------------------------------------------------------
// Kernel B (sequential scan): one workgroup, 768 threads = 12 waves (3/SIMD).
// tid -> row = tid>>1 (0..383), khalf = tid&1 (64-wide k slice).
//
// WHY THIS SHAPE (R11 lesson): the scan is VALU-ISSUE-bound. Busy cycles
// were ~1150/CU/step across all 512-thr variants vs a 384-cyc FMA floor;
// ~770 cyc was per-wave overhead, dominated by the GATE BLOCK (~150
// cyc/wave: 3 exp + 3 rcp + arith) issued by ALL 8 waves because gate
// lanes (kseg==0) lived in every wave. Here:
//  - combine = ONE DPP xor1 stage (row sum completed within a lane pair)
//  - gates run in a WAVE-UNIFORM `tid<128` block: issued by 2 of 12
//    waves only; other waves branch straight to the barrier
//  - per-thread overhead (acc init, reduction) amortized over 12 waves
// Census: matvec ~560 cyc/SIMD + serial gate phase ~300 -> ~900/step.
//
// *** NUMERICS: scalar fmaf ONLY (R7/R8: packed v_pk_fma_f32 failed twice
// at 0.28125 -- not bit-exact on this toolchain). Row tree here:
// float4 chain over k in [khalf*64, khalf*64+64), (x+y)+(z+w), then
// s += partner via DPP xor1 (both lanes compute the same sum).
// Deterministic; every scalar-fma tree so far has passed.
//
// Retained guards: literal weight indices (dynamic idx spills -- R2);
// raw "lgkmcnt(0); s_barrier" (keeps prefetch loads in flight -- R4);
// depth-2 two-set gate-input prefetch, incremental pointers (R8).
// LDS banks: matvec b128 reads = 2 distinct addresses/instr (2-way
// multicast, free per m136); hg writes/reads lane-consecutive.
// ---------------------------------------------------------------------------
__device__ __forceinline__ void fma4(float4& acc, const float4& wv, const float4& hv)
{
    acc.x = fmaf(wv.x, hv.x, acc.x);
    acc.y = fmaf(wv.y, hv.y, acc.y);
    acc.z = fmaf(wv.z, hv.z, acc.z);
    acc.w = fmaf(wv.w, hv.w, acc.w);
}

__device__ __forceinline__ float dpp_xor1_add(float x)
{
    float t = __int_as_float(
        __builtin_amdgcn_mov_dpp(__float_as_int(x), 0xB1, 0xF, 0xF, true)); // [1,0,3,2]
    return x + t;
}

__device__ __forceinline__ void fast_barrier()
{
    asm volatile("s_waitcnt lgkmcnt(0)\n\ts_barrier" ::: "memory");
}

__device__ __forceinline__ float gru_gate(float c0, float c1, float c2,
                                          float s0, float s1, float s2,
                                          float bn, float hprev)
{
    float er = __expf(-(c0 + s0));
    float r = __builtin_amdgcn_rcpf(1.f + er);
    float ez = __expf(-(c1 + s1));
    float z = __builtin_amdgcn_rcpf(1.f + ez);
    float xn = c2 + r * (s2 + bn);
    float e2 = __expf(-2.f * fabsf(xn));
    float th = (1.f - e2) * __builtin_amdgcn_rcpf(1.f + e2);
    float nn = copysignf(th, xn);
    return nn + z * (hprev - nn);
}

__global__ __launch_bounds__(768, 3)
void scan_kernel(const float* __restrict__ ig, const float* __restrict__ h0,
                 const float* __restrict__ w_hh, const float* __restrict__ b_n,
                 float* __restrict__ hlin, int T)
{
    __shared__ __align__(16) float hs[HID];   // hidden state
    __shared__ float hg[H3];                  // row pre-activations

    const int tid = threadIdx.x;     // 0..767
    const int row = tid >> 1;        // 0..383
    const int khalf = tid & 1;       // 0..1 (64-wide k slice)

    // this thread's 64 weights (16 float4) -> registers, literal indices
    float4 w[16];
    {
        const float4* wb = (const float4*)(w_hh + (size_t)row * HID + khalf * 64);
#pragma unroll
        for (int k = 0; k < 16; k++) w[k] = wb[k];
    }
    if (tid < HID) hs[tid] = h0[tid];

    // gate-input registers live in threads 0..127 (waves 0,1 only)
    float bn = 0.f;
    float p00 = 0.f, p01 = 0.f, p02 = 0.f;  // set 0 (even steps)
    float p10 = 0.f, p11 = 0.f, p12 = 0.f;  // set 1 (odd steps)
    const float* pf = ig + (size_t)2 * H3 + tid;  // -> ig[(s+2)*H3 + j]
    float* hl = hlin + tid;                        // -> hlin[s*LIN_IN + j]
    if (tid < HID) {
        bn = b_n[tid];
        p00 = ig[tid];
        p01 = ig[HID + tid];
        p02 = ig[2 * HID + tid];
        const float* q = ig + H3;
        p10 = q[tid];
        p11 = q[HID + tid];
        p12 = q[2 * HID + tid];
    }
    __syncthreads();

    const float4* hp = (const float4*)hs + khalf * 16;

#define STEP(C0, C1, C2, DO_PREFETCH)                                          \
    {                                                                          \
        float4 acc = {0.f, 0.f, 0.f, 0.f};                                     \
        _Pragma("unroll")                                                      \
        for (int kk = 0; kk < 16; kk++)                                        \
            fma4(acc, w[kk], hp[kk]);                                          \
        float s = (acc.x + acc.y) + (acc.z + acc.w);                           \
        s = dpp_xor1_add(s);     /* s = khalf0 + khalf1 (both lanes) */        \
        if (khalf == 0) hg[row] = s;                                           \
        fast_barrier();                                                        \
        if (tid < HID) {  /* wave-uniform: waves 0,1 only */                   \
            float hr = hg[tid];                                                \
            float hz = hg[HID + tid];                                          \
            float hn = hg[2 * HID + tid];                                      \
            float hprev = hs[tid];                                             \
            float hnew = gru_gate(C0, C1, C2, hr, hz, hn, bn, hprev);          \
            hs[tid] = hnew;                                                    \
            if (tid < LIN_IN) *hl = hnew;                                      \
            if (DO_PREFETCH) {  /* refill this set for step+2 */               \
                C0 = pf[0];                                                    \
                C1 = pf[HID];                                                  \
                C2 = pf[2 * HID];                                              \
            }                                                                  \
            hl += LIN_IN;                                                      \
            pf += H3;                                                          \
        }                                                                      \
        fast_barrier();                                                        \
    }

    int s = 0;
    for (; s + 4 <= T; s += 2) {           // both halves may prefetch
        STEP(p00, p01, p02, true)
        STEP(p10, p11, p12, true)
    }
    // tail: last two steps, no prefetch
    STEP(p00, p01, p02, false)
    STEP(p10, p11, p12, false)
#undef STEP
}

// ---------------------------------------------------------------------------
// Kernel C (parallel): out[t] = dot(hlin[t,:], xlin[t,:]) + lbias
// ---------------------------------------------------------------------------
__global__ __launch_bounds__(256)
void readout_kernel(const float* __restrict__ hlin, const float* __restrict__ xlin,
                    const float* __restrict__ lbias, float* __restrict__ out, int T)
{
    int gid = blockIdx.x * 256 + threadIdx.x;
    int t = gid >> 3;
    int seg = gid & 7;
    if (t < T) {
        float4 hv = ((const float4*)hlin)[(size_t)t * 8 + seg];
        float4 xv = ((const float4*)xlin)[(size_t)t * 8 + seg];
        float p = hv.x * xv.x + hv.y * xv.y + hv.z * xv.z + hv.w * xv.w;
        p += __shfl_xor(p, 1);
        p += __shfl_xor(p, 2);
        p += __shfl_xor(p, 4);
        if (seg == 0) out[t] = p + lbias[0];
    }
}

extern "C" void kernel_launch(void* const* d_in, const int* in_sizes, int n_in,
                              void* d_out, int out_size, void* d_ws, size_t ws_size,
                              hipStream_t stream) {
    const float* x_gru = (const float*)d_in[0];  // (T, 96)
    const float* x_lin = (const float*)d_in[1];  // (T, 32)
    const float* h0    = (const float*)d_in[2];  // (128,)
    const float* w_ih  = (const float*)d_in[3];  // (384, 96)
    const float* w_hh  = (const float*)d_in[4];  // (384, 128)
    const float* b_ih  = (const float*)d_in[5];  // (384,)
    const float* b_n   = (const float*)d_in[6];  // (128,)
    const float* lbias = (const float*)d_in[7];  // (1,)
    float* out = (float*)d_out;                  // (T, 1)

    int T = in_sizes[0] / IN_SIZE;               // 65536 (even)
    float* igates = (float*)d_ws;                    // T*384 floats = 96 MiB
    float* hlin   = (float*)d_ws + (size_t)T * H3;   // T*32 floats  =  8 MiB

    igates_kernel<<<T / 16, 384, 0, stream>>>(x_gru, w_ih, b_ih, igates, T);
    scan_kernel<<<1, 768, 0, stream>>>(igates, h0, w_hh, b_n, hlin, T);
    readout_kernel<<<(T * 8 + 255) / 256, 256, 0, stream>>>(hlin, x_lin, lbias, out, T);
}

// Round 15
// 45768.100 us; speedup vs baseline: 1.3276x; 1.3276x over previous
//
#include <hip/hip_runtime.h>
#include <math.h>

#define IN_SIZE 96
#define HID 128
#define H3 384
#define LIN_IN 32

// ---------------------------------------------------------------------------
// Kernel A (parallel): igates[t][j] = dot(input_GRU[t,:], w_ih[j,:]) + b_ih[j]
// ---------------------------------------------------------------------------
__global__ __launch_bounds__(384, 2)
void igates_kernel(const float* __restrict__ x, const float* __restrict__ w_ih,
                   const float* __restrict__ b_ih, float* __restrict__ ig, int T)
{
    const int TT = 16;
    int t0 = blockIdx.x * TT;
    int j = threadIdx.x; // 0..383
    __shared__ __align__(16) float xs[TT * IN_SIZE]; // 6 KB
    for (int idx = j; idx < TT * IN_SIZE; idx += H3)
        xs[idx] = x[(size_t)t0 * IN_SIZE + idx];
    __syncthreads();

    float acc[TT];
    float b = b_ih[j];
#pragma unroll
    for (int tt = 0; tt < TT; tt++) acc[tt] = b;

    const float4* w4 = (const float4*)(w_ih + (size_t)j * IN_SIZE);
#pragma unroll
    for (int k = 0; k < IN_SIZE / 4; k++) {
        float4 wv = w4[k];
#pragma unroll
        for (int tt = 0; tt < TT; tt++) {
            const float4* xv4 = (const float4*)(xs + tt * IN_SIZE);
            float4 xv = xv4[k];
            acc[tt] = fmaf(wv.x, xv.x, acc[tt]);
            acc[tt] = fmaf(wv.y, xv.y, acc[tt]);
            acc[tt] = fmaf(wv.z, xv.z, acc[tt]);
            acc[tt] = fmaf(wv.w, xv.w, acc[tt]);
        }
    }
#pragma unroll
    for (int tt = 0; tt < TT; tt++)
        ig[(size_t)(t0 + tt) * H3 + j] = acc[tt];
}

// ---------------------------------------------------------------------------
// Kernel B (sequential scan): one workgroup, 512 threads = 8 waves (2/SIMD).
// tid -> g = tid>>3 (0..63: units g and g+64), kseg = tid&7 (16-wide k slice).
// Each thread: 6 w_hh rows {g, g+128, g+256, g+64, g+192, g+320} x 16 k.
//
// WHY 8-WAY K-SPLIT (R14 lesson): the matvec phase is LDS-RETURN-BANDWIDTH
// bound (~85-90 B/cyc/CU measured across R6/R14; broadcasts are NOT
// deduplicated -- cost is per lane-byte). Traffic = threads x slice bytes:
//   R14 768thr x 256B = 196KB/step -> saturated, 60.8ms
//   R6  512thr x 128B =  64KB/step -> ~770 cyc matvec phase, 31.9ms
//   here 512thr x  64B =  32KB/step -> ~360 cyc < FMA issue 384
// so the matvec phase flips to FMA-issue-bound (the scalar floor).
//
// LDS LAYOUT: hs in 8 segments of 16 floats, stride SPAD=20. Per matvec
// instruction (fixed kk), the 8 kseg addresses hit banks (20*kseg+4*kk)%32
// = all 32 banks exactly once -> conflict-free (R14's unpadded layout put
// 2 addresses per bank quad: 5e7 conflicts).
//
// COMBINE: xor1+xor2 via quad_perm DPP (pure VALU -- R4: __shfl_xor lowers
// to ds_bpermute, slow), then ONE ds_swizzle xor4 stage (0x101F), 6 values
// in parallel. Row sums complete in-register; gates need no LDS roundtrip.
//
// *** NUMERICS: scalar fmaf ONLY (R7/R8: v_pk_fma_f32 failed twice at
// 0.28125). Tree: 4-float4 fmaf chain per 16-k slice, (x+y)+(z+w), then
// +xor1, +xor2, +xor4. New deterministic tree, same scalar family as the
// five passing trees (absmax 0.016-0.0625). ***
//
// Retained guards: literal weight indices (R2: dynamic idx -> scratch
// spill); raw "lgkmcnt(0); s_barrier" (R4: __syncthreads drains vmcnt and
// kills prefetch); depth-2 two-set gate-input prefetch, incremental
// pointers (R8); ONE barrier per step (R6).
// ---------------------------------------------------------------------------
__device__ __forceinline__ void fma4(float4& acc, const float4& wv, const float4& hv)
{
    acc.x = fmaf(wv.x, hv.x, acc.x);
    acc.y = fmaf(wv.y, hv.y, acc.y);
    acc.z = fmaf(wv.z, hv.z, acc.z);
    acc.w = fmaf(wv.w, hv.w, acc.w);
}

__device__ __forceinline__ float octet_sum(float x)
{
    float t;
    t = __int_as_float(__builtin_amdgcn_mov_dpp(__float_as_int(x), 0xB1, 0xF, 0xF, true)); // xor1
    x += t;
    t = __int_as_float(__builtin_amdgcn_mov_dpp(__float_as_int(x), 0x4E, 0xF, 0xF, true)); // xor2
    x += t;
    t = __int_as_float(__builtin_amdgcn_ds_swizzle(__float_as_int(x), 0x101F));            // xor4
    x += t;
    return x;
}

__device__ __forceinline__ void fast_barrier()
{
    asm volatile("s_waitcnt lgkmcnt(0)\n\ts_barrier" ::: "memory");
}

__device__ __forceinline__ float gru_gate(float c0, float c1, float c2,
                                          float s0, float s1, float s2,
                                          float bn, float hprev)
{
    float er = __expf(-(c0 + s0));
    float r = __builtin_amdgcn_rcpf(1.f + er);
    float ez = __expf(-(c1 + s1));
    float z = __builtin_amdgcn_rcpf(1.f + ez);
    float xn = c2 + r * (s2 + bn);
    float e2 = __expf(-2.f * fabsf(xn));
    float th = (1.f - e2) * __builtin_amdgcn_rcpf(1.f + e2);
    float nn = copysignf(th, xn);
    return nn + z * (hprev - nn);
}

#define SPAD 20  // 16 floats per k-segment + 4 pad

__global__ __launch_bounds__(512, 2)
void scan_kernel(const float* __restrict__ ig, const float* __restrict__ h0,
                 const float* __restrict__ w_hh, const float* __restrict__ b_n,
                 float* __restrict__ hlin, int T)
{
    __shared__ __align__(16) float hs[8 * SPAD];   // padded h (640 B)

    const int tid = threadIdx.x;     // 0..511
    const int g = tid >> 3;          // 0..63 (units g and g+64)
    const int kseg = tid & 7;        // 0..7  (16-wide k slice)
    const bool gate_lane = (kseg == 0);

    // 6 rows x 16 k -> 24 float4 in registers (literal indices only)
    float4 wA0[4], wA1[4], wA2[4], wB0[4], wB1[4], wB2[4];
    {
        const float* bA0 = w_hh + (size_t)g * HID + kseg * 16;
        const float* bA1 = w_hh + (size_t)(g + HID) * HID + kseg * 16;
        const float* bA2 = w_hh + (size_t)(g + 2 * HID) * HID + kseg * 16;
        const float* bB0 = w_hh + (size_t)(g + 64) * HID + kseg * 16;
        const float* bB1 = w_hh + (size_t)(g + 64 + HID) * HID + kseg * 16;
        const float* bB2 = w_hh + (size_t)(g + 64 + 2 * HID) * HID + kseg * 16;
#pragma unroll
        for (int k = 0; k < 4; k++) {
            wA0[k] = ((const float4*)bA0)[k];
            wA1[k] = ((const float4*)bA1)[k];
            wA2[k] = ((const float4*)bA2)[k];
            wB0[k] = ((const float4*)bB0)[k];
            wB1[k] = ((const float4*)bB1)[k];
            wB2[k] = ((const float4*)bB2)[k];
        }
    }
    if (tid < HID) hs[(tid >> 4) * SPAD + (tid & 15)] = h0[tid];

    // gate inputs for units A=g, B=g+64; sets 0 (even step) / 1 (odd step)
    float bnA = 0.f, bnB = 0.f;
    float pA00 = 0.f, pA01 = 0.f, pA02 = 0.f, pA10 = 0.f, pA11 = 0.f, pA12 = 0.f;
    float pB00 = 0.f, pB01 = 0.f, pB02 = 0.f, pB10 = 0.f, pB11 = 0.f, pB12 = 0.f;
    if (gate_lane) {
        bnA = b_n[g];
        bnB = b_n[g + 64];
        pA00 = ig[g];            pB00 = ig[g + 64];
        pA01 = ig[HID + g];      pB01 = ig[HID + g + 64];
        pA02 = ig[2 * HID + g];  pB02 = ig[2 * HID + g + 64];
        const float* q = ig + H3;
        pA10 = q[g];             pB10 = q[g + 64];
        pA11 = q[HID + g];       pB11 = q[HID + g + 64];
        pA12 = q[2 * HID + g];   pB12 = q[2 * HID + g + 64];
    }
    __syncthreads();

    const float4* hp = (const float4*)(hs + kseg * SPAD);  // 80B stride, 16B aligned
    const int hwA = (g >> 4) * SPAD + (g & 15);            // unit g slot
    const int hwB = hwA + 4 * SPAD;                        // unit g+64 slot

    // incrementally-advanced prefetch bases: ig[(s+2)*H3 + ...]
    const float* pfA = ig + (size_t)2 * H3 + g;
    const float* pfB = pfA + 64;
    float* hl = hlin + g;  // hlin[step*LIN_IN + g]

#define STEP(A0, A1, A2, B0, B1, B2, DO_PREFETCH)                              \
    {                                                                          \
        float hprevA = 0.f, hprevB = 0.f;                                      \
        if (gate_lane) { hprevA = hs[hwA]; hprevB = hs[hwB]; }                 \
        float4 aA0 = {0.f, 0.f, 0.f, 0.f}, aA1 = aA0, aA2 = aA0;               \
        float4 aB0 = aA0, aB1 = aA0, aB2 = aA0;                                \
        _Pragma("unroll")                                                      \
        for (int kk = 0; kk < 4; kk++) {                                       \
            float4 hv = hp[kk];                                                \
            fma4(aA0, wA0[kk], hv);                                            \
            fma4(aA1, wA1[kk], hv);                                            \
            fma4(aA2, wA2[kk], hv);                                            \
            fma4(aB0, wB0[kk], hv);                                            \
            fma4(aB1, wB1[kk], hv);                                            \
            fma4(aB2, wB2[kk], hv);                                            \
        }                                                                      \
        float sA0 = (aA0.x + aA0.y) + (aA0.z + aA0.w);                         \
        float sA1 = (aA1.x + aA1.y) + (aA1.z + aA1.w);                         \
        float sA2 = (aA2.x + aA2.y) + (aA2.z + aA2.w);                         \
        float sB0 = (aB0.x + aB0.y) + (aB0.z + aB0.w);                         \
        float sB1 = (aB1.x + aB1.y) + (aB1.z + aB1.w);                         \
        float sB2 = (aB2.x + aB2.y) + (aB2.z + aB2.w);                         \
        sA0 = octet_sum(sA0); sA1 = octet_sum(sA1); sA2 = octet_sum(sA2);      \
        sB0 = octet_sum(sB0); sB1 = octet_sum(sB1); sB2 = octet_sum(sB2);      \
        if (gate_lane) {                                                       \
            float hnewA = gru_gate(A0, A1, A2, sA0, sA1, sA2, bnA, hprevA);    \
            float hnewB = gru_gate(B0, B1, B2, sB0, sB1, sB2, bnB, hprevB);    \
            hs[hwA] = hnewA;                                                   \
            hs[hwB] = hnewB;                                                   \
            if (g < LIN_IN) *hl = hnewA;                                       \
            if (DO_PREFETCH) {  /* refill this set for step+2 */               \
                A0 = pfA[0];                                                   \
                A1 = pfA[HID];                                                 \
                A2 = pfA[2 * HID];                                             \
                B0 = pfB[0];                                                   \
                B1 = pfB[HID];                                                 \
                B2 = pfB[2 * HID];                                             \
            }                                                                  \
        }                                                                      \
        hl += LIN_IN;                                                          \
        pfA += H3;                                                             \
        pfB += H3;                                                             \
        fast_barrier();                                                        \
    }

    int s = 0;
    for (; s + 4 <= T; s += 2) {           // both halves may prefetch
        STEP(pA00, pA01, pA02, pB00, pB01, pB02, true)
        STEP(pA10, pA11, pA12, pB10, pB11, pB12, true)
    }
    // tail: last two steps, no prefetch
    STEP(pA00, pA01, pA02, pB00, pB01, pB02, false)
    STEP(pA10, pA11, pA12, pB10, pB11, pB12, false)
#undef STEP
}

// ---------------------------------------------------------------------------
// Kernel C (parallel): out[t] = dot(hlin[t,:], xlin[t,:]) + lbias
// ---------------------------------------------------------------------------
__global__ __launch_bounds__(256)
void readout_kernel(const float* __restrict__ hlin, const float* __restrict__ xlin,
                    const float* __restrict__ lbias, float* __restrict__ out, int T)
{
    int gid = blockIdx.x * 256 + threadIdx.x;
    int t = gid >> 3;
    int seg = gid & 7;
    if (t < T) {
        float4 hv = ((const float4*)hlin)[(size_t)t * 8 + seg];
        float4 xv = ((const float4*)xlin)[(size_t)t * 8 + seg];
        float p = hv.x * xv.x + hv.y * xv.y + hv.z * xv.z + hv.w * xv.w;
        p += __shfl_xor(p, 1);
        p += __shfl_xor(p, 2);
        p += __shfl_xor(p, 4);
        if (seg == 0) out[t] = p + lbias[0];
    }
}

extern "C" void kernel_launch(void* const* d_in, const int* in_sizes, int n_in,
                              void* d_out, int out_size, void* d_ws, size_t ws_size,
                              hipStream_t stream) {
    const float* x_gru = (const float*)d_in[0];  // (T, 96)
    const float* x_lin = (const float*)d_in[1];  // (T, 32)
    const float* h0    = (const float*)d_in[2];  // (128,)
    const float* w_ih  = (const float*)d_in[3];  // (384, 96)
    const float* w_hh  = (const float*)d_in[4];  // (384, 128)
    const float* b_ih  = (const float*)d_in[5];  // (384,)
    const float* b_n   = (const float*)d_in[6];  // (128,)
    const float* lbias = (const float*)d_in[7];  // (1,)
    float* out = (float*)d_out;                  // (T, 1)

    int T = in_sizes[0] / IN_SIZE;               // 65536 (even)
    float* igates = (float*)d_ws;                    // T*384 floats = 96 MiB
    float* hlin   = (float*)d_ws + (size_t)T * H3;   // T*32 floats  =  8 MiB

    igates_kernel<<<T / 16, 384, 0, stream>>>(x_gru, w_ih, b_ih, igates, T);
    scan_kernel<<<1, 512, 0, stream>>>(igates, h0, w_hh, b_n, hlin, T);
    readout_kernel<<<(T * 8 + 255) / 256, 256, 0, stream>>>(hlin, x_lin, lbias, out, T);
}

// Round 16
// 34813.986 us; speedup vs baseline: 1.7453x; 1.3146x over previous
//
#include <hip/hip_runtime.h>
#include <math.h>

#define IN_SIZE 96
#define HID 128
#define H3 384
#define LIN_IN 32

// ---------------------------------------------------------------------------
// Kernel A (parallel): igates[t][j] = dot(input_GRU[t,:], w_ih[j,:]) + b_ih[j]
// ---------------------------------------------------------------------------
__global__ __launch_bounds__(384, 2)
void igates_kernel(const float* __restrict__ x, const float* __restrict__ w_ih,
                   const float* __restrict__ b_ih, float* __restrict__ ig, int T)
{
    const int TT = 16;
    int t0 = blockIdx.x * TT;
    int j = threadIdx.x; // 0..383
    __shared__ __align__(16) float xs[TT * IN_SIZE]; // 6 KB
    for (int idx = j; idx < TT * IN_SIZE; idx += H3)
        xs[idx] = x[(size_t)t0 * IN_SIZE + idx];
    __syncthreads();

    float acc[TT];
    float b = b_ih[j];
#pragma unroll
    for (int tt = 0; tt < TT; tt++) acc[tt] = b;

    const float4* w4 = (const float4*)(w_ih + (size_t)j * IN_SIZE);
#pragma unroll
    for (int k = 0; k < IN_SIZE / 4; k++) {
        float4 wv = w4[k];
#pragma unroll
        for (int tt = 0; tt < TT; tt++) {
            const float4* xv4 = (const float4*)(xs + tt * IN_SIZE);
            float4 xv = xv4[k];
            acc[tt] = fmaf(wv.x, xv.x, acc[tt]);
            acc[tt] = fmaf(wv.y, xv.y, acc[tt]);
            acc[tt] = fmaf(wv.z, xv.z, acc[tt]);
            acc[tt] = fmaf(wv.w, xv.w, acc[tt]);
        }
    }
#pragma unroll
    for (int tt = 0; tt < TT; tt++)
        ig[(size_t)(t0 + tt) * H3 + j] = acc[tt];
}

// ---------------------------------------------------------------------------
// Kernel B (sequential scan): one workgroup, 512 threads = 8 waves (2/SIMD).
// tid -> j = tid>>2 (hidden unit), kseg = tid&3 (32-wide k slice).
// R9's matvec partition (best measured: 31.9 ms, 1168 cyc/step) with ONE
// structural change:
//
// WAVE-UNIFORM GATE PHASE (R15/R11 synthesis): per-CU VALU issue is the
// pole (~1150 cyc/step invariant across R6/R9/R11/R15 tilings), and its
// largest removable block is the gate+prefetch code (~450-600 cyc/CU)
// issued MASKED BY ALL 8 WAVES because gate lanes (kseg==0) lived in
// every wave. Now:
//   phase 1 (all waves): matvec + quad-DPP combine; after quad_sum all
//     4 quad lanes hold IDENTICAL bits, so lane kseg=c (c<3) writes gate
//     c with one masked ds_write_b32 -> hg[c*128+j].
//   fast_barrier
//   phase 2 (tid<128 -- waves 0,1 ONLY; waves 2-7 s_cbranch_execz to the
//     barrier): gates, hs/hlin write, depth-2 prefetch refill.
//   fast_barrier
// This is R4's two-phase shape minus its two poisons: bpermute combine
// (R4 regression) and vmcnt-draining __syncthreads (R3 regression).
//
// *** NUMERICS FROZEN: bit-identical to the R9 31.9ms passing kernel.
// Scalar fmaf only (R7/R8: v_pk_fma_f32 failed twice at 0.28125), float4
// accumulators, (x+y)+(z+w), quad_sum DPP (all lanes same bits), gru_gate
// unchanged. s0..s2 ride through LDS bitwise-preserved. ***
//
// Retained guards: literal weight indices (R2: dynamic idx -> scratch);
// raw "lgkmcnt(0); s_barrier" (R4: vmcnt drain kills prefetch); depth-2
// two-set prefetch, incremental pointers (R8); padded h for the matvec
// (R3: 0 conflicts); no LDS-pipe cross-lane ops (R4/R15: bpermute and
// ds_swizzle on the serial path both regressed).
// ---------------------------------------------------------------------------
__device__ __forceinline__ void fma4(float4& acc, const float4& wv, const float4& hv)
{
    acc.x = fmaf(wv.x, hv.x, acc.x);
    acc.y = fmaf(wv.y, hv.y, acc.y);
    acc.z = fmaf(wv.z, hv.z, acc.z);
    acc.w = fmaf(wv.w, hv.w, acc.w);
}

__device__ __forceinline__ float quad_sum(float x)
{
    float t;
    t = __int_as_float(__builtin_amdgcn_mov_dpp(__float_as_int(x), 0xB1, 0xF, 0xF, true)); // [1,0,3,2]
    x += t;
    t = __int_as_float(__builtin_amdgcn_mov_dpp(__float_as_int(x), 0x4E, 0xF, 0xF, true)); // [2,3,0,1]
    x += t;
    return x;
}

__device__ __forceinline__ void fast_barrier()
{
    asm volatile("s_waitcnt lgkmcnt(0)\n\ts_barrier" ::: "memory");
}

__device__ __forceinline__ float gru_gate(float c0, float c1, float c2,
                                          float s0, float s1, float s2,
                                          float bn, float hprev)
{
    float er = __expf(-(c0 + s0));
    float r = __builtin_amdgcn_rcpf(1.f + er);
    float ez = __expf(-(c1 + s1));
    float z = __builtin_amdgcn_rcpf(1.f + ez);
    float xn = c2 + r * (s2 + bn);
    float e2 = __expf(-2.f * fabsf(xn));
    float th = (1.f - e2) * __builtin_amdgcn_rcpf(1.f + e2);
    float nn = copysignf(th, xn);
    return nn + z * (hprev - nn);
}

#define HPAD 36  // 32 floats per k-segment + 4 pad

__global__ __launch_bounds__(512, 2)
void scan_kernel(const float* __restrict__ ig, const float* __restrict__ h0,
                 const float* __restrict__ w_hh, const float* __restrict__ b_n,
                 float* __restrict__ hlin, int T)
{
    __shared__ __align__(16) float hs[4 * HPAD];   // padded h (matvec reads)
    __shared__ float hg[H3];                       // row pre-activations

    const int tid = threadIdx.x;     // 0..511
    const int j = tid >> 2;          // 0..127
    const int kseg = tid & 3;        // 0..3

    // weights for rows j, j+128, j+256 (k slice kseg*32..+32) -> registers
    float4 w0[8], w1[8], w2[8];
    {
        const float* b0 = w_hh + (size_t)j * HID + kseg * 32;
        const float* b1 = w_hh + (size_t)(j + HID) * HID + kseg * 32;
        const float* b2 = w_hh + (size_t)(j + 2 * HID) * HID + kseg * 32;
#pragma unroll
        for (int k = 0; k < 8; k++) {
            w0[k] = ((const float4*)b0)[k];
            w1[k] = ((const float4*)b1)[k];
            w2[k] = ((const float4*)b2)[k];
        }
    }
    if (tid < HID) hs[(tid >> 5) * HPAD + (tid & 31)] = h0[tid];

    // gate-input registers (live only in waves 0,1 = tid<128)
    float bn = 0.f;
    float p00 = 0.f, p01 = 0.f, p02 = 0.f;  // set 0 (even steps)
    float p10 = 0.f, p11 = 0.f, p12 = 0.f;  // set 1 (odd steps)
    const float* pf = ig + (size_t)2 * H3 + tid;  // -> ig[(s+2)*H3 + tid]
    float* hl = hlin + tid;                        // -> hlin[s*LIN_IN + tid]
    if (tid < HID) {
        bn = b_n[tid];
        p00 = ig[tid];
        p01 = ig[HID + tid];
        p02 = ig[2 * HID + tid];
        const float* q = ig + H3;
        p10 = q[tid];
        p11 = q[HID + tid];
        p12 = q[2 * HID + tid];
    }
    __syncthreads();

    const float4* hp = (const float4*)(hs + kseg * HPAD);
    const int hwidx = (tid >> 5) * HPAD + (tid & 31);  // gate thread's h slot

#define STEP(C0, C1, C2, DO_PREFETCH)                                          \
    {                                                                          \
        float4 a0 = {0.f, 0.f, 0.f, 0.f}, a1 = a0, a2 = a0;                    \
        _Pragma("unroll")                                                      \
        for (int kk = 0; kk < 8; kk++) {                                       \
            float4 hv = hp[kk];                                                \
            fma4(a0, w0[kk], hv);                                              \
            fma4(a1, w1[kk], hv);                                              \
            fma4(a2, w2[kk], hv);                                              \
        }                                                                      \
        float s0 = (a0.x + a0.y) + (a0.z + a0.w);                              \
        float s1 = (a1.x + a1.y) + (a1.z + a1.w);                              \
        float s2 = (a2.x + a2.y) + (a2.z + a2.w);                              \
        s0 = quad_sum(s0); s1 = quad_sum(s1); s2 = quad_sum(s2);               \
        /* all 4 quad lanes hold identical bits; lane c<3 writes gate c */     \
        float sv = (kseg == 1) ? s1 : ((kseg == 2) ? s2 : s0);                 \
        if (kseg < 3) hg[kseg * HID + j] = sv;                                 \
        fast_barrier();                                                        \
        if (tid < HID) {  /* wave-uniform: waves 0,1 only */                   \
            float hr = hg[tid];                                                \
            float hz = hg[HID + tid];                                          \
            float hn = hg[2 * HID + tid];                                      \
            float hprev = hs[hwidx];                                           \
            float hnew = gru_gate(C0, C1, C2, hr, hz, hn, bn, hprev);          \
            hs[hwidx] = hnew;                                                  \
            if (tid < LIN_IN) *hl = hnew;                                      \
            if (DO_PREFETCH) {  /* refill this set for step+2 */               \
                C0 = pf[0];                                                    \
                C1 = pf[HID];                                                  \
                C2 = pf[2 * HID];                                              \
            }                                                                  \
            hl += LIN_IN;                                                      \
            pf += H3;                                                          \
        }                                                                      \
        fast_barrier();                                                        \
    }

    int s = 0;
    for (; s + 4 <= T; s += 2) {           // both halves may prefetch
        STEP(p00, p01, p02, true)
        STEP(p10, p11, p12, true)
    }
    // tail: last two steps, no prefetch
    STEP(p00, p01, p02, false)
    STEP(p10, p11, p12, false)
#undef STEP
}

// ---------------------------------------------------------------------------
// Kernel C (parallel): out[t] = dot(hlin[t,:], xlin[t,:]) + lbias
// ---------------------------------------------------------------------------
__global__ __launch_bounds__(256)
void readout_kernel(const float* __restrict__ hlin, const float* __restrict__ xlin,
                    const float* __restrict__ lbias, float* __restrict__ out, int T)
{
    int gid = blockIdx.x * 256 + threadIdx.x;
    int t = gid >> 3;
    int seg = gid & 7;
    if (t < T) {
        float4 hv = ((const float4*)hlin)[(size_t)t * 8 + seg];
        float4 xv = ((const float4*)xlin)[(size_t)t * 8 + seg];
        float p = hv.x * xv.x + hv.y * xv.y + hv.z * xv.z + hv.w * xv.w;
        p += __shfl_xor(p, 1);
        p += __shfl_xor(p, 2);
        p += __shfl_xor(p, 4);
        if (seg == 0) out[t] = p + lbias[0];
    }
}

extern "C" void kernel_launch(void* const* d_in, const int* in_sizes, int n_in,
                              void* d_out, int out_size, void* d_ws, size_t ws_size,
                              hipStream_t stream) {
    const float* x_gru = (const float*)d_in[0];  // (T, 96)
    const float* x_lin = (const float*)d_in[1];  // (T, 32)
    const float* h0    = (const float*)d_in[2];  // (128,)
    const float* w_ih  = (const float*)d_in[3];  // (384, 96)
    const float* w_hh  = (const float*)d_in[4];  // (384, 128)
    const float* b_ih  = (const float*)d_in[5];  // (384,)
    const float* b_n   = (const float*)d_in[6];  // (128,)
    const float* lbias = (const float*)d_in[7];  // (1,)
    float* out = (float*)d_out;                  // (T, 1)

    int T = in_sizes[0] / IN_SIZE;               // 65536 (even)
    float* igates = (float*)d_ws;                    // T*384 floats = 96 MiB
    float* hlin   = (float*)d_ws + (size_t)T * H3;   // T*32 floats  =  8 MiB

    igates_kernel<<<T / 16, 384, 0, stream>>>(x_gru, w_ih, b_ih, igates, T);
    scan_kernel<<<1, 512, 0, stream>>>(igates, h0, w_hh, b_n, hlin, T);
    readout_kernel<<<(T * 8 + 255) / 256, 256, 0, stream>>>(hlin, x_lin, lbias, out, T);
}

// Round 17
// 31914.041 us; speedup vs baseline: 1.9039x; 1.0909x over previous
//
#include <hip/hip_runtime.h>
#include <math.h>

#define IN_SIZE 96
#define HID 128
#define H3 384
#define LIN_IN 32

// ---------------------------------------------------------------------------
// Kernel A (parallel): igates[t][j] = dot(input_GRU[t,:], w_ih[j,:]) + b_ih[j]
// ---------------------------------------------------------------------------
__global__ __launch_bounds__(384, 2)
void igates_kernel(const float* __restrict__ x, const float* __restrict__ w_ih,
                   const float* __restrict__ b_ih, float* __restrict__ ig, int T)
{
    const int TT = 16;
    int t0 = blockIdx.x * TT;
    int j = threadIdx.x; // 0..383
    __shared__ __align__(16) float xs[TT * IN_SIZE]; // 6 KB
    for (int idx = j; idx < TT * IN_SIZE; idx += H3)
        xs[idx] = x[(size_t)t0 * IN_SIZE + idx];
    __syncthreads();

    float acc[TT];
    float b = b_ih[j];
#pragma unroll
    for (int tt = 0; tt < TT; tt++) acc[tt] = b;

    const float4* w4 = (const float4*)(w_ih + (size_t)j * IN_SIZE);
#pragma unroll
    for (int k = 0; k < IN_SIZE / 4; k++) {
        float4 wv = w4[k];
#pragma unroll
        for (int tt = 0; tt < TT; tt++) {
            const float4* xv4 = (const float4*)(xs + tt * IN_SIZE);
            float4 xv = xv4[k];
            acc[tt] = fmaf(wv.x, xv.x, acc[tt]);
            acc[tt] = fmaf(wv.y, xv.y, acc[tt]);
            acc[tt] = fmaf(wv.z, xv.z, acc[tt]);
            acc[tt] = fmaf(wv.w, xv.w, acc[tt]);
        }
    }
#pragma unroll
    for (int tt = 0; tt < TT; tt++)
        ig[(size_t)(t0 + tt) * H3 + j] = acc[tt];
}

// ---------------------------------------------------------------------------
// Kernel B (sequential scan): one workgroup, 512 threads = 8 waves (2/SIMD).
// tid -> j = tid>>2 (hidden unit), kseg = tid&3 (32-wide k slice).
// Thread owns all three gate rows {j, j+128, j+256}; quad DPP k-combine puts
// hr,hz,hn in the kseg==0 lane which computes hnew[j]: one barrier/step.
//
// *** BEST MEASURED SHAPE (R10: 31.9 ms, 1168 cyc/step, on-CU VALU ~99%) ***
// Structural survey (R11/R14/R15/R16) all regressed:
//  - 256thr 1 wave/SIMD: no TLP, +40% (R11)
//  - 768thr: LDS return-BW saturated (196KB/step), +90% (R14)
//  - 8-way k-split + ds_swizzle combine: LDS-pipe on serial path, +43% (R15)
//  - two-phase wave-uniform gates: -165 busy but +272 idle (2nd barrier +
//    latency-exposed 2-wave gate phase), +9% (R16)
// DO NOT RESTRUCTURE. The issue port is the pole and it is saturated.
//
// *** NUMERICS ARE FROZEN (R7/R8) ***: scalar fmaf only (packed
// v_pk_fma_f32 failed twice at absmax 0.28125); float4 accumulators,
// (x+y)+(z+w), quad_sum DPP. DO NOT TOUCH THE ARITHMETIC.
//
// Guards: literal weight indices (R2: dynamic idx -> scratch spill);
// raw "lgkmcnt(0); s_barrier" (R4: __syncthreads drains vmcnt, kills
// prefetch); depth-2 two-set prefetch, incremental pointers (R8);
// padded h layout hs[kseg*36+off] (R3: 0 bank conflicts);
// amdgpu_waves_per_eu(2,2) (R10: 256-reg class, VGPR 88).
// ---------------------------------------------------------------------------
__device__ __forceinline__ void fma4(float4& acc, const float4& wv, const float4& hv)
{
    acc.x = fmaf(wv.x, hv.x, acc.x);
    acc.y = fmaf(wv.y, hv.y, acc.y);
    acc.z = fmaf(wv.z, hv.z, acc.z);
    acc.w = fmaf(wv.w, hv.w, acc.w);
}

__device__ __forceinline__ float quad_sum(float x)
{
    float t;
    t = __int_as_float(__builtin_amdgcn_mov_dpp(__float_as_int(x), 0xB1, 0xF, 0xF, true)); // [1,0,3,2]
    x += t;
    t = __int_as_float(__builtin_amdgcn_mov_dpp(__float_as_int(x), 0x4E, 0xF, 0xF, true)); // [2,3,0,1]
    x += t;
    return x;
}

__device__ __forceinline__ void fast_barrier()
{
    asm volatile("s_waitcnt lgkmcnt(0)\n\ts_barrier" ::: "memory");
}

#define HPAD 36  // 32 floats per k-segment + 4 pad

__global__
__attribute__((amdgpu_flat_work_group_size(512, 512), amdgpu_waves_per_eu(2, 2)))
void scan_kernel(const float* __restrict__ ig, const float* __restrict__ h0,
                 const float* __restrict__ w_hh, const float* __restrict__ b_n,
                 float* __restrict__ hlin, int T)
{
    __shared__ __align__(16) float hs[4 * HPAD];

    const int tid = threadIdx.x;     // 0..511
    const int j = tid >> 2;          // 0..127
    const int kseg = tid & 3;        // 0..3
    const bool gate_lane = (kseg == 0);

    // weights for rows j, j+128, j+256 (k slice kseg*32..+32) -> registers
    float4 w0[8], w1[8], w2[8];
    {
        const float* b0 = w_hh + (size_t)j * HID + kseg * 32;
        const float* b1 = w_hh + (size_t)(j + HID) * HID + kseg * 32;
        const float* b2 = w_hh + (size_t)(j + 2 * HID) * HID + kseg * 32;
#pragma unroll
        for (int k = 0; k < 8; k++) {
            w0[k] = ((const float4*)b0)[k];
            w1[k] = ((const float4*)b1)[k];
            w2[k] = ((const float4*)b2)[k];
        }
    }
    if (tid < HID) hs[(tid >> 5) * HPAD + (tid & 31)] = h0[tid];

    // two gate-input register sets: P0 = even step, P1 = odd step
    float bn = 0.f;
    float p00 = 0.f, p01 = 0.f, p02 = 0.f;  // set 0
    float p10 = 0.f, p11 = 0.f, p12 = 0.f;  // set 1
    if (gate_lane) {
        bn = b_n[j];
        p00 = ig[j];
        p01 = ig[HID + j];
        p02 = ig[2 * HID + j];
        const float* q = ig + H3;
        p10 = q[j];
        p11 = q[HID + j];
        p12 = q[2 * HID + j];
    }
    __syncthreads();

    const float4* hp = (const float4*)(hs + kseg * HPAD);
    const int hwidx = (j >> 5) * HPAD + (j & 31);

    // incrementally-advanced prefetch base: points at ig[(s+2)*H3 + j]
    const float* pf = ig + (size_t)2 * H3 + j;
    float* hl = hlin + j;  // hlin[step*LIN_IN + j], advanced by LIN_IN

#define MATVEC_GATES(C0, C1, C2, DO_PREFETCH)                                  \
    {                                                                          \
        float4 a0 = {0.f, 0.f, 0.f, 0.f}, a1 = a0, a2 = a0;                    \
        _Pragma("unroll")                                                      \
        for (int kk = 0; kk < 8; kk++) {                                       \
            float4 hv = hp[kk];                                                \
            fma4(a0, w0[kk], hv);                                              \
            fma4(a1, w1[kk], hv);                                              \
            fma4(a2, w2[kk], hv);                                              \
        }                                                                      \
        float s0 = (a0.x + a0.y) + (a0.z + a0.w);                              \
        float s1 = (a1.x + a1.y) + (a1.z + a1.w);                              \
        float s2 = (a2.x + a2.y) + (a2.z + a2.w);                              \
        s0 = quad_sum(s0); s1 = quad_sum(s1); s2 = quad_sum(s2);               \
        if (gate_lane) {                                                       \
            float hprev = hs[hwidx];                                           \
            float er = __expf(-(C0 + s0));                                     \
            float r = __builtin_amdgcn_rcpf(1.f + er);                         \
            float ez = __expf(-(C1 + s1));                                     \
            float z = __builtin_amdgcn_rcpf(1.f + ez);                         \
            float xn = C2 + r * (s2 + bn);                                     \
            float e2 = __expf(-2.f * fabsf(xn));                               \
            float th = (1.f - e2) * __builtin_amdgcn_rcpf(1.f + e2);           \
            float nn = copysignf(th, xn);                                      \
            float hnew = nn + z * (hprev - nn);                                \
            hs[hwidx] = hnew;                                                  \
            if (j < LIN_IN) *hl = hnew;                                        \
            if (DO_PREFETCH) {  /* refill this set for step+2 */               \
                C0 = pf[0];                                                    \
                C1 = pf[HID];                                                  \
                C2 = pf[2 * HID];                                              \
            }                                                                  \
        }                                                                      \
        hl += LIN_IN;                                                          \
        pf += H3;                                                              \
        fast_barrier();                                                        \
    }

    int s = 0;
    for (; s + 4 <= T; s += 2) {           // both halves may prefetch
        MATVEC_GATES(p00, p01, p02, true)
        MATVEC_GATES(p10, p11, p12, true)
    }
    // tail: last two steps, no prefetch (uniform, outside the hot loop)
    MATVEC_GATES(p00, p01, p02, false)
    MATVEC_GATES(p10, p11, p12, false)
#undef MATVEC_GATES
}

// ---------------------------------------------------------------------------
// Kernel C (parallel): out[t] = dot(hlin[t,:], xlin[t,:]) + lbias
// ---------------------------------------------------------------------------
__global__ __launch_bounds__(256)
void readout_kernel(const float* __restrict__ hlin, const float* __restrict__ xlin,
                    const float* __restrict__ lbias, float* __restrict__ out, int T)
{
    int gid = blockIdx.x * 256 + threadIdx.x;
    int t = gid >> 3;
    int seg = gid & 7;
    if (t < T) {
        float4 hv = ((const float4*)hlin)[(size_t)t * 8 + seg];
        float4 xv = ((const float4*)xlin)[(size_t)t * 8 + seg];
        float p = hv.x * xv.x + hv.y * xv.y + hv.z * xv.z + hv.w * xv.w;
        p += __shfl_xor(p, 1);
        p += __shfl_xor(p, 2);
        p += __shfl_xor(p, 4);
        if (seg == 0) out[t] = p + lbias[0];
    }
}

extern "C" void kernel_launch(void* const* d_in, const int* in_sizes, int n_in,
                              void* d_out, int out_size, void* d_ws, size_t ws_size,
                              hipStream_t stream) {
    const float* x_gru = (const float*)d_in[0];  // (T, 96)
    const float* x_lin = (const float*)d_in[1];  // (T, 32)
    const float* h0    = (const float*)d_in[2];  // (128,)
    const float* w_ih  = (const float*)d_in[3];  // (384, 96)
    const float* w_hh  = (const float*)d_in[4];  // (384, 128)
    const float* b_ih  = (const float*)d_in[5];  // (384,)
    const float* b_n   = (const float*)d_in[6];  // (128,)
    const float* lbias = (const float*)d_in[7];  // (1,)
    float* out = (float*)d_out;                  // (T, 1)

    int T = in_sizes[0] / IN_SIZE;               // 65536 (even)
    float* igates = (float*)d_ws;                    // T*384 floats = 96 MiB
    float* hlin   = (float*)d_ws + (size_t)T * H3;   // T*32 floats  =  8 MiB

    igates_kernel<<<T / 16, 384, 0, stream>>>(x_gru, w_ih, b_ih, igates, T);
    scan_kernel<<<1, 512, 0, stream>>>(igates, h0, w_hh, b_n, hlin, T);
    readout_kernel<<<(T * 8 + 255) / 256, 256, 0, stream>>>(hlin, x_lin, lbias, out, T);
}